// Round 5
// baseline (552.111 us; speedup 1.0000x reference)
//
#include <hip/hip_runtime.h>
#include <hip/hip_bf16.h>
#include <math.h>

#define BB 8
#define CC 64
#define NN 500
#define TT 12
#define HH 4
#define FF 64
#define CT (CC*TT)      // 768
#define HF (HH*FF)      // 256
#define NBT (HH*TT)     // 48
#define NBHT (BB*NBT)   // 384
#define NROWS (BB*HH*TT*NN)  // 192000
#define NNODE (BB*NN)   // 4000
#define DSTRIDE 128     // padded adjacency row stride (max deg ~50 << 128)

typedef unsigned short ushort_t;
typedef __attribute__((ext_vector_type(8))) short short8;
typedef __attribute__((ext_vector_type(4))) float floatx4;

static __device__ __forceinline__ ushort_t f2bf(float v) {
    __hip_bfloat16 h = __float2bfloat16(v);
    ushort_t u;
    __builtin_memcpy(&u, &h, 2);
    return u;
}

// ---------------------------------------------------------------------------
// K0: padded adjacency list of mask = (adj + I) > 0. Wave per row.
// ---------------------------------------------------------------------------
__global__ __launch_bounds__(256) void k0_build(const float* __restrict__ adj,
                                                int* __restrict__ deg,
                                                int* __restrict__ cols) {
    int wid  = threadIdx.x >> 6;
    int lane = threadIdx.x & 63;
    int n = blockIdx.x * 4 + wid;
    if (n >= NN) return;

    int* myc = cols + n * DSTRIDE;
    int base = 0;
    for (int m0 = 0; m0 < NN; m0 += 64) {
        int m = m0 + lane;
        bool pred = false;
        if (m < NN) {
            float v = adj[n*NN + m];
            pred = (v > 0.f) || (m == n);
        }
        unsigned long long mask = __ballot(pred);
        int pos = base + __popcll(mask & ((1ull << lane) - 1ull));
        if (pred) myc[pos] = m;
        base += __popcll(mask);
    }
    if (lane == 0) deg[n] = base;
}

// ---------------------------------------------------------------------------
// K6: transpose x [B,C,N,T] -> xT [(b*N+n)*768 + c*12 + t] (node-major).
// ---------------------------------------------------------------------------
__global__ __launch_bounds__(256) void k6_xt(const float* __restrict__ x,
                                             float* __restrict__ xT) {
    __shared__ float tile[16*776];   // 49664 B
    int b  = blockIdx.x >> 5;
    int n0 = (blockIdx.x & 31) * 16;
    for (int idx = threadIdx.x; idx < CC*16*TT; idx += 256) {
        int c   = idx / (16*TT);
        int rem = idx % (16*TT);
        int nl  = rem / TT;
        int t   = rem % TT;
        int n   = n0 + nl;
        if (n < NN)
            tile[nl*776 + c*TT + t] = x[((b*CC + c)*NN + n)*TT + t];
    }
    __syncthreads();
    for (int idx = threadIdx.x; idx < 16*CT; idx += 256) {
        int nl = idx / CT;
        int j  = idx % CT;
        int n  = n0 + nl;
        if (n < NN)
            xT[(size_t)(b*NN + n)*CT + j] = tile[nl*776 + j];
    }
}

// ---------------------------------------------------------------------------
// K1: prep. p1/p2 folded attention vectors; WmT transpose; WgB = bf16(Wg).
// ---------------------------------------------------------------------------
__global__ __launch_bounds__(256) void k1_prep(const float* __restrict__ W,
                                               const float* __restrict__ a1,
                                               const float* __restrict__ a2,
                                               const float* __restrict__ Wm,
                                               const float* __restrict__ Wg,
                                               float* __restrict__ p1,
                                               float* __restrict__ p2,
                                               float* __restrict__ WmT,
                                               ushort_t* __restrict__ WgB) {
    int idx = blockIdx.x * 256 + threadIdx.x;
    if (idx < HH*CC) {
        int h = idx / CC, c = idx % CC;
        float s1 = 0.f, s2 = 0.f;
        for (int f = 0; f < FF; ++f) {
            float w = W[(h*CC + c)*FF + f];
            s1 += w * a1[h*FF + f];
            s2 += w * a2[h*FF + f];
        }
        p1[idx] = s1; p2[idx] = s2;
    }
    int j = idx - HH*CC;
    if (j >= 0 && j < 3*CC*CC) {
        int c = j >> 6, o = j & 63;
        WmT[j] = Wm[o*(3*CC) + c];
    }
    int j2 = idx - (HH*CC + 3*CC*CC);
    if (j2 >= 0 && j2 < FF*HF) {
        WgB[j2] = f2bf(Wg[j2]);
    }
}

// ---------------------------------------------------------------------------
// K2: Wh[bht][n][f] (bf16) = sum_c h[node][c,t] * W[h,c,f]; e1/e2 via p1/p2.
// (unchanged from R4)
// ---------------------------------------------------------------------------
__global__ __launch_bounds__(256) void k2_wh_e(const float* __restrict__ hin,
                                               const float* __restrict__ W,
                                               const float* __restrict__ p1,
                                               const float* __restrict__ p2,
                                               __hip_bfloat16* __restrict__ Wh,
                                               float* __restrict__ e1,
                                               float* __restrict__ e2) {
    __shared__ float hL[4][CT];
    int wid  = threadIdx.x >> 6;
    int lane = threadIdx.x & 63;
    int gidx = blockIdx.x * 4 + wid;
    int b = gidx / NN, n = gidx % NN;

    {
        const float4* src = (const float4*)(hin + (size_t)gidx * CT);
        float4* dst = (float4*)hL[wid];
        for (int i = lane; i < CT/4; i += 64) dst[i] = src[i];
    }
    __syncthreads();

    const float*  hLw = hL[wid];
    const float4* h4  = (const float4*)hLw;
    int h  = lane >> 4;
    int fb = lane & 15;

    float acc[4][TT];
    #pragma unroll
    for (int q = 0; q < 4; ++q)
        #pragma unroll
        for (int t = 0; t < TT; ++t) acc[q][t] = 0.f;

    for (int c = 0; c < CC; ++c) {
        float4 v0 = h4[c*3+0], v1 = h4[c*3+1], v2 = h4[c*3+2];
        float hv[12] = {v0.x,v0.y,v0.z,v0.w, v1.x,v1.y,v1.z,v1.w,
                        v2.x,v2.y,v2.z,v2.w};
        const float* Wc = W + (h*CC + c)*FF + fb;
        float w0 = Wc[0], w1 = Wc[16], w2 = Wc[32], w3 = Wc[48];
        #pragma unroll
        for (int t = 0; t < TT; ++t) {
            acc[0][t] += hv[t]*w0;
            acc[1][t] += hv[t]*w1;
            acc[2][t] += hv[t]*w2;
            acc[3][t] += hv[t]*w3;
        }
    }
    #pragma unroll
    for (int q = 0; q < 4; ++q) {
        int f = fb + 16*q;
        #pragma unroll
        for (int t = 0; t < TT; ++t) {
            Wh[((size_t)((b*HH + h)*TT + t)*NN + n)*FF + f] =
                __float2bfloat16(acc[q][t]);
        }
    }

    int t2 = lane & 15;
    if (t2 < TT) {
        int h2 = lane >> 4;
        float s1 = 0.f, s2 = 0.f;
        for (int c = 0; c < CC; ++c) {
            float v = hLw[c*TT + t2];
            s1 += v * p1[h2*CC + c];
            s2 += v * p2[h2*CC + c];
        }
        int idx = ((b*HH + h2)*TT + t2)*NN + n;
        e1[idx] = s1;
        e2[idx] = s2;
    }
}

// ---------------------------------------------------------------------------
// K2T: Wh[bht][n<500][64] -> WhT[bht][f=64][m=512] bf16, m>=500 zeroed.
// Stage-in: lane = one m-row, reads 16B f-octet (L1-amortized across octets),
// writes LDS at consecutive-m addresses (2 lanes/bank = conflict-free).
// ---------------------------------------------------------------------------
__global__ __launch_bounds__(256) void k2t(const ushort_t* __restrict__ Wh,
                                           ushort_t* __restrict__ WhT) {
    __shared__ ushort_t tile[64*512];     // 64 KB
    int wid  = threadIdx.x >> 6;
    int lane = threadIdx.x & 63;
    int bht  = blockIdx.x;
    const ushort_t* src = Wh + (size_t)bht * NN * FF;

    for (int task = wid; task < 64; task += 4) {
        int i  = task >> 3;               // m-block of 64
        int fo = task & 7;                // f-octet
        int m  = i*64 + lane;
        short8 v = {0,0,0,0,0,0,0,0};
        if (m < NN) v = *(const short8*)(src + m*FF + fo*8);
        #pragma unroll
        for (int j = 0; j < 8; ++j)
            tile[(fo*8 + j)*512 + m] = (ushort_t)v[j];
    }
    __syncthreads();

    ushort_t* dst = WhT + (size_t)bht * 64 * 512;
    for (int f = wid; f < 64; f += 4) {
        short8 v = *(const short8*)&tile[f*512 + lane*8];
        *(short8*)(dst + f*512 + lane*8) = v;
    }
}

// ---------------------------------------------------------------------------
// K3: attention PV via MFMA. One block per bht; wave-private dense A-tiles.
// A[16 n-rows][512 m] bf16 in LDS (XOR-swizzle m ^= row*8 vs bank stride),
// B-frags = 16B contiguous loads from WhT (global, L2-hot), lsum via a
// constant all-ones B fragment (C_ones[row] = sum_m exp). Softmax is
// shift-free (scores O(1)); zero A entries contribute exactly 0.
// ---------------------------------------------------------------------------
__global__ __launch_bounds__(256) void k3_attn(const ushort_t* __restrict__ WhT,
                                               const float* __restrict__ e1,
                                               const float* __restrict__ e2,
                                               const int* __restrict__ deg,
                                               const int* __restrict__ cols,
                                               ushort_t* __restrict__ hprB) {
    __shared__ ushort_t A[4][16*512];     // 4 x 16 KB = 64 KB
    int wid  = threadIdx.x >> 6;
    int lane = threadIdx.x & 63;
    int bht  = blockIdx.x;
    int b    = bht / NBT;
    int ht   = bht % NBT;

    const float* e1p = e1 + (size_t)bht * NN;
    const float* e2p = e2 + (size_t)bht * NN;
    const ushort_t* WT = WhT + (size_t)bht * 64 * 512;
    ushort_t* Aw = A[wid];

    int quad = lane >> 4;                 // 0..3
    int r    = lane & 15;                 // A-row / B-col / C-col

    const short8 ONES = {0x3F80,0x3F80,0x3F80,0x3F80,
                         0x3F80,0x3F80,0x3F80,0x3F80}; // bf16 1.0 x8

    for (int rt = wid; rt < 32; rt += 4) {
        int n0 = rt * 16;

        // zero A-tile (16 b128 writes)
        {
            short8 z = {0,0,0,0,0,0,0,0};
            short8* Az = (short8*)Aw;
            for (int i = lane; i < 16*512/8; i += 64) Az[i] = z;
        }
        __builtin_amdgcn_s_waitcnt(0);    // lgkm drain before scatter (same wave)

        // build dense exp rows (one row per iteration, 4 in flight)
        #pragma unroll 4
        for (int rr = 0; rr < 16; ++rr) {
            int n = n0 + rr;
            if (n < NN) {
                int dg = deg[n];
                float e1v = e1p[n];
                int s = lane;
                if (s < dg) {
                    int m = cols[n*DSTRIDE + s];
                    float sc = e1v + e2p[m];
                    sc = sc > 0.f ? sc : 0.2f*sc;
                    Aw[rr*512 + (m ^ (rr*8))] = f2bf(__expf(sc));
                }
                for (int s2 = 64 + lane; s2 < dg; s2 += 64) {   // deg>64 safety
                    int m = cols[n*DSTRIDE + s2];
                    float sc = e1v + e2p[m];
                    sc = sc > 0.f ? sc : 0.2f*sc;
                    Aw[rr*512 + (m ^ (rr*8))] = f2bf(__expf(sc));
                }
            }
        }

        // MFMA K-loop
        floatx4 C[4];
        floatx4 Cs = {0.f,0.f,0.f,0.f};
        #pragma unroll
        for (int ft = 0; ft < 4; ++ft) C[ft] = (floatx4){0.f,0.f,0.f,0.f};

        #pragma unroll
        for (int kc = 0; kc < 16; ++kc) {
            int kbase = kc*32 + quad*8;
            short8 a = *(const short8*)&Aw[r*512 + (kbase ^ (r*8))];
            #pragma unroll
            for (int ft = 0; ft < 4; ++ft) {
                short8 bfr = *(const short8*)(WT + (size_t)(ft*16 + r)*512 + kbase);
                C[ft] = __builtin_amdgcn_mfma_f32_16x16x32_bf16(a, bfr, C[ft], 0, 0, 0);
            }
            Cs = __builtin_amdgcn_mfma_f32_16x16x32_bf16(a, ONES, Cs, 0, 0, 0);
        }

        // epilogue: scale by 1/lsum, ELU, store bf16 node-major
        #pragma unroll
        for (int reg = 0; reg < 4; ++reg) {
            int row = quad*4 + reg;
            int n = n0 + row;
            if (n < NN) {
                float inv = 1.0f / Cs[reg];
                size_t base = ((size_t)(b*NN + n)*NBT + ht)*FF;
                #pragma unroll
                for (int ft = 0; ft < 4; ++ft) {
                    float v = C[ft][reg] * inv;
                    v = v > 0.f ? v : __expf(v) - 1.f;
                    hprB[base + ft*16 + r] = f2bf(v);
                }
            }
        }
    }
}

// ---------------------------------------------------------------------------
// K4: head-mix 1x1 conv + residual via MFMA. A = WgB (bf16, in 128 VGPRs,
// loaded once per wave), B = hprB rows (16B contiguous). t = lane&15 clamped
// to 11 for B loads: C cols 12..15 are junk but never read. No LDS.
// Block = 4 waves x 4 nodes each -> 16 nodes/block.
// ---------------------------------------------------------------------------
__global__ __launch_bounds__(256) void k4_mfma(const ushort_t* __restrict__ hprB,
                                               const ushort_t* __restrict__ WgB,
                                               const float* __restrict__ bg,
                                               const float* __restrict__ xT,
                                               float* __restrict__ hnext) {
    int wid  = threadIdx.x >> 6;
    int lane = threadIdx.x & 63;
    int quad = lane >> 4;
    int r    = lane & 15;

    // A fragments: Afr[ot][kc] = WgB[o = ot*16 + r][k = kc*32 + quad*8 .. +7]
    short8 Afr[4][8];
    #pragma unroll
    for (int ot = 0; ot < 4; ++ot)
        #pragma unroll
        for (int kc = 0; kc < 8; ++kc)
            Afr[ot][kc] = *(const short8*)(WgB + (size_t)(ot*16 + r)*HF + kc*32 + quad*8);

    float4 bgv[4];
    #pragma unroll
    for (int ot = 0; ot < 4; ++ot)
        bgv[ot] = *(const float4*)(bg + ot*16 + quad*4);

    int tcl = r < TT ? r : TT-1;          // clamp for B address

    for (int u = 0; u < 4; ++u) {
        int node = blockIdx.x*16 + wid*4 + u;
        const ushort_t* P = hprB + (size_t)node * (NBT*FF);

        floatx4 C[4];
        #pragma unroll
        for (int ot = 0; ot < 4; ++ot) C[ot] = (floatx4){0.f,0.f,0.f,0.f};

        #pragma unroll
        for (int kc = 0; kc < 8; ++kc) {
            int k = kc*32 + quad*8;
            int h = k >> 6, f0 = k & 63;
            short8 bfr = *(const short8*)(P + (h*TT + tcl)*FF + f0);
            #pragma unroll
            for (int ot = 0; ot < 4; ++ot)
                C[ot] = __builtin_amdgcn_mfma_f32_16x16x32_bf16(Afr[ot][kc], bfr, C[ot], 0, 0, 0);
        }

        if (r < TT) {
            float* hout = hnext + (size_t)node * CT;
            const float* xp = xT + (size_t)node * CT;
            #pragma unroll
            for (int ot = 0; ot < 4; ++ot) {
                #pragma unroll
                for (int reg = 0; reg < 4; ++reg) {
                    int o = ot*16 + quad*4 + reg;
                    float v = C[ot][reg] + bgv[ot][reg];
                    hout[o*TT + r] = 0.05f*xp[o*TT + r] + 0.95f*v;
                }
            }
        }
    }
}

// ---------------------------------------------------------------------------
// K5: final mix (unchanged). out = bm + Wm @ [xT|h1|h2] per node.
// ---------------------------------------------------------------------------
__global__ __launch_bounds__(256) void k5_final(const float* __restrict__ xT,
                                                const float* __restrict__ h1,
                                                const float* __restrict__ h2,
                                                const float* __restrict__ WmT,
                                                const float* __restrict__ bm,
                                                float* __restrict__ out) {
    __shared__ float sL[4][3][CT];
    int wid  = threadIdx.x >> 6;
    int lane = threadIdx.x & 63;
    int gidx = blockIdx.x * 4 + wid;
    int b = gidx / NN, n = gidx % NN;

    {
        const float4* s0 = (const float4*)(xT + (size_t)gidx*CT);
        const float4* s1 = (const float4*)(h1 + (size_t)gidx*CT);
        const float4* s2 = (const float4*)(h2 + (size_t)gidx*CT);
        float4* d0 = (float4*)sL[wid][0];
        float4* d1 = (float4*)sL[wid][1];
        float4* d2 = (float4*)sL[wid][2];
        for (int i = lane; i < CT/4; i += 64) {
            d0[i] = s0[i]; d1[i] = s1[i]; d2[i] = s2[i];
        }
    }
    __syncthreads();

    float (*S)[CT] = sL[wid];
    int ob = lane & 15;
    int tq = lane >> 4;

    float acc[4][3];
    #pragma unroll
    for (int oi = 0; oi < 4; ++oi) {
        float bv = bm[ob + 16*oi];
        #pragma unroll
        for (int ti = 0; ti < 3; ++ti) acc[oi][ti] = bv;
    }

    for (int c = 0; c < CC; ++c) {
        float v0[3], v1[3], v2[3];
        #pragma unroll
        for (int ti = 0; ti < 3; ++ti) {
            int t = tq + 4*ti;
            v0[ti] = S[0][c*TT + t];
            v1[ti] = S[1][c*TT + t];
            v2[ti] = S[2][c*TT + t];
        }
        #pragma unroll
        for (int oi = 0; oi < 4; ++oi) {
            int o = ob + 16*oi;
            float w0 = WmT[(c       )*64 + o];
            float w1 = WmT[(CC  + c )*64 + o];
            float w2 = WmT[(2*CC + c)*64 + o];
            #pragma unroll
            for (int ti = 0; ti < 3; ++ti) {
                acc[oi][ti] += v0[ti]*w0 + v1[ti]*w1 + v2[ti]*w2;
            }
        }
    }

    #pragma unroll
    for (int oi = 0; oi < 4; ++oi) {
        int o = ob + 16*oi;
        #pragma unroll
        for (int ti = 0; ti < 3; ++ti) {
            int t = tq + 4*ti;
            out[((b*CC + o)*NN + n)*TT + t] = acc[oi][ti];
        }
    }
}

// ---------------------------------------------------------------------------
extern "C" void kernel_launch(void* const* d_in, const int* in_sizes, int n_in,
                              void* d_out, int out_size, void* d_ws, size_t ws_size,
                              hipStream_t stream) {
    const float* x   = (const float*)d_in[0];
    const float* adj = (const float*)d_in[1];
    const float* W   = (const float*)d_in[2];
    const float* a1  = (const float*)d_in[3];
    const float* a2  = (const float*)d_in[4];
    const float* Wg  = (const float*)d_in[5];
    const float* bg  = (const float*)d_in[6];
    const float* Wm  = (const float*)d_in[7];
    const float* bm  = (const float*)d_in[8];
    float* out = (float*)d_out;

    char* ws = (char*)d_ws;
    size_t off = 0;
    auto alloc = [&](size_t bytes) -> void* {
        void* p = ws + off;
        off += (bytes + 255) & ~(size_t)255;
        return p;
    };

    int*   deg  = (int*)  alloc(NN * sizeof(int));
    int*   cols = (int*)  alloc((size_t)NN * DSTRIDE * sizeof(int));
    float* p1   = (float*)alloc(HH*CC * sizeof(float));
    float* p2   = (float*)alloc(HH*CC * sizeof(float));
    float* WmT  = (float*)alloc(3*CC*CC * sizeof(float));
    ushort_t* WgB = (ushort_t*)alloc((size_t)FF*HF * 2);
    float* xT   = (float*)alloc((size_t)NNODE * CT * sizeof(float));        // 12.3 MB
    ushort_t* Wh   = (ushort_t*)alloc((size_t)NROWS * FF * 2);              // 24.6 MB
    ushort_t* WhT  = (ushort_t*)alloc((size_t)NBHT * 64 * 512 * 2);         // 25.2 MB
    ushort_t* hprB = (ushort_t*)alloc((size_t)NNODE * NBT * FF * 2);        // 24.6 MB
    float* e1   = (float*)alloc((size_t)NROWS * sizeof(float));
    float* e2   = (float*)alloc((size_t)NROWS * sizeof(float));
    float* h1   = (float*)alloc((size_t)NNODE * CT * sizeof(float));        // 12.3 MB
    float* h2   = (float*)alloc((size_t)NNODE * CT * sizeof(float));        // 12.3 MB
    (void)ws_size;

    k0_build<<<125, 256, 0, stream>>>(adj, deg, cols);
    k6_xt   <<<256, 256, 0, stream>>>(x, xT);
    k1_prep <<<114, 256, 0, stream>>>(W, a1, a2, Wm, Wg, p1, p2, WmT, WgB);

    // layer 1
    k2_wh_e <<<NNODE/4, 256, 0, stream>>>(xT, W, p1, p2, (__hip_bfloat16*)Wh, e1, e2);
    k2t     <<<NBHT,    256, 0, stream>>>(Wh, WhT);
    k3_attn <<<NBHT,    256, 0, stream>>>(WhT, e1, e2, deg, cols, hprB);
    k4_mfma <<<NNODE/16,256, 0, stream>>>(hprB, WgB, bg, xT, h1);

    // layer 2
    k2_wh_e <<<NNODE/4, 256, 0, stream>>>(h1, W, p1, p2, (__hip_bfloat16*)Wh, e1, e2);
    k2t     <<<NBHT,    256, 0, stream>>>(Wh, WhT);
    k3_attn <<<NBHT,    256, 0, stream>>>(WhT, e1, e2, deg, cols, hprB);
    k4_mfma <<<NNODE/16,256, 0, stream>>>(hprB, WgB, bg, xT, h2);

    // final
    k5_final<<<NNODE/4, 256, 0, stream>>>(xT, h1, h2, WmT, bm, out);
}

// Round 6
// 454.955 us; speedup vs baseline: 1.2136x; 1.2136x over previous
//
#include <hip/hip_runtime.h>
#include <hip/hip_bf16.h>
#include <math.h>

#define BB 8
#define CC 64
#define NN 500
#define TT 12
#define HH 4
#define FF 64
#define CT (CC*TT)      // 768
#define HF (HH*FF)      // 256
#define NBT (HH*TT)     // 48
#define NBHT (BB*NBT)   // 384
#define NROWS (BB*HH*TT*NN)  // 192000
#define NNODE (BB*NN)   // 4000
#define DSTRIDE 128     // padded adjacency row stride (max deg ~50 << 128)
#define AST 136         // A-chunk row stride in ushorts (136*2=272B = 17 banks-quads -> 2-way only)

typedef unsigned short ushort_t;
typedef __attribute__((ext_vector_type(8))) short short8;
typedef __attribute__((ext_vector_type(4))) float floatx4;

static __device__ __forceinline__ ushort_t f2bf(float v) {
    __hip_bfloat16 h = __float2bfloat16(v);
    ushort_t u;
    __builtin_memcpy(&u, &h, 2);
    return u;
}

// ---------------------------------------------------------------------------
// K0: padded adjacency list of mask = (adj + I) > 0. Wave per row.
// cols within a row are ASCENDING (block-ascending + lane-ascending).
// Also records cstart4[n] = first edge index of m-chunks {0,128,256,384}.
// ---------------------------------------------------------------------------
__global__ __launch_bounds__(256) void k0_build(const float* __restrict__ adj,
                                                int* __restrict__ deg,
                                                int* __restrict__ cols,
                                                int4* __restrict__ cstart) {
    int wid  = threadIdx.x >> 6;
    int lane = threadIdx.x & 63;
    int n = blockIdx.x * 4 + wid;
    if (n >= NN) return;

    int* myc = cols + n * DSTRIDE;
    int base = 0;
    int cs0 = 0, cs1 = 0, cs2 = 0, cs3 = 0;
    for (int m0 = 0; m0 < NN; m0 += 64) {
        if (m0 == 128) cs1 = base;
        if (m0 == 256) cs2 = base;
        if (m0 == 384) cs3 = base;
        int m = m0 + lane;
        bool pred = false;
        if (m < NN) {
            float v = adj[n*NN + m];
            pred = (v > 0.f) || (m == n);
        }
        unsigned long long mask = __ballot(pred);
        int pos = base + __popcll(mask & ((1ull << lane) - 1ull));
        if (pred) myc[pos] = m;
        base += __popcll(mask);
    }
    if (lane == 0) {
        deg[n] = base;
        cstart[n] = make_int4(cs0, cs1, cs2, cs3);
    }
}

// ---------------------------------------------------------------------------
// K6: transpose x [B,C,N,T] -> xT [(b*N+n)*768 + c*12 + t] (node-major).
// ---------------------------------------------------------------------------
__global__ __launch_bounds__(256) void k6_xt(const float* __restrict__ x,
                                             float* __restrict__ xT) {
    __shared__ float tile[16*776];   // 49664 B
    int b  = blockIdx.x >> 5;
    int n0 = (blockIdx.x & 31) * 16;
    for (int idx = threadIdx.x; idx < CC*16*TT; idx += 256) {
        int c   = idx / (16*TT);
        int rem = idx % (16*TT);
        int nl  = rem / TT;
        int t   = rem % TT;
        int n   = n0 + nl;
        if (n < NN)
            tile[nl*776 + c*TT + t] = x[((b*CC + c)*NN + n)*TT + t];
    }
    __syncthreads();
    for (int idx = threadIdx.x; idx < 16*CT; idx += 256) {
        int nl = idx / CT;
        int j  = idx % CT;
        int n  = n0 + nl;
        if (n < NN)
            xT[(size_t)(b*NN + n)*CT + j] = tile[nl*776 + j];
    }
}

// ---------------------------------------------------------------------------
// K1: prep. p1/p2 folded attention vectors; WmT transpose; WgB = bf16(Wg).
// ---------------------------------------------------------------------------
__global__ __launch_bounds__(256) void k1_prep(const float* __restrict__ W,
                                               const float* __restrict__ a1,
                                               const float* __restrict__ a2,
                                               const float* __restrict__ Wm,
                                               const float* __restrict__ Wg,
                                               float* __restrict__ p1,
                                               float* __restrict__ p2,
                                               float* __restrict__ WmT,
                                               ushort_t* __restrict__ WgB) {
    int idx = blockIdx.x * 256 + threadIdx.x;
    if (idx < HH*CC) {
        int h = idx / CC, c = idx % CC;
        float s1 = 0.f, s2 = 0.f;
        for (int f = 0; f < FF; ++f) {
            float w = W[(h*CC + c)*FF + f];
            s1 += w * a1[h*FF + f];
            s2 += w * a2[h*FF + f];
        }
        p1[idx] = s1; p2[idx] = s2;
    }
    int j = idx - HH*CC;
    if (j >= 0 && j < 3*CC*CC) {
        int c = j >> 6, o = j & 63;
        WmT[j] = Wm[o*(3*CC) + c];
    }
    int j2 = idx - (HH*CC + 3*CC*CC);
    if (j2 >= 0 && j2 < FF*HF) {
        WgB[j2] = f2bf(Wg[j2]);
    }
}

// ---------------------------------------------------------------------------
// K2: Wh[bht][n][f] (bf16) = sum_c h[node][c,t] * W[h,c,f]; e1/e2 via p1/p2.
// ---------------------------------------------------------------------------
__global__ __launch_bounds__(256) void k2_wh_e(const float* __restrict__ hin,
                                               const float* __restrict__ W,
                                               const float* __restrict__ p1,
                                               const float* __restrict__ p2,
                                               __hip_bfloat16* __restrict__ Wh,
                                               float* __restrict__ e1,
                                               float* __restrict__ e2) {
    __shared__ float hL[4][CT];
    int wid  = threadIdx.x >> 6;
    int lane = threadIdx.x & 63;
    int gidx = blockIdx.x * 4 + wid;
    int b = gidx / NN, n = gidx % NN;

    {
        const float4* src = (const float4*)(hin + (size_t)gidx * CT);
        float4* dst = (float4*)hL[wid];
        for (int i = lane; i < CT/4; i += 64) dst[i] = src[i];
    }
    __syncthreads();

    const float*  hLw = hL[wid];
    const float4* h4  = (const float4*)hLw;
    int h  = lane >> 4;
    int fb = lane & 15;

    float acc[4][TT];
    #pragma unroll
    for (int q = 0; q < 4; ++q)
        #pragma unroll
        for (int t = 0; t < TT; ++t) acc[q][t] = 0.f;

    for (int c = 0; c < CC; ++c) {
        float4 v0 = h4[c*3+0], v1 = h4[c*3+1], v2 = h4[c*3+2];
        float hv[12] = {v0.x,v0.y,v0.z,v0.w, v1.x,v1.y,v1.z,v1.w,
                        v2.x,v2.y,v2.z,v2.w};
        const float* Wc = W + (h*CC + c)*FF + fb;
        float w0 = Wc[0], w1 = Wc[16], w2 = Wc[32], w3 = Wc[48];
        #pragma unroll
        for (int t = 0; t < TT; ++t) {
            acc[0][t] += hv[t]*w0;
            acc[1][t] += hv[t]*w1;
            acc[2][t] += hv[t]*w2;
            acc[3][t] += hv[t]*w3;
        }
    }
    #pragma unroll
    for (int q = 0; q < 4; ++q) {
        int f = fb + 16*q;
        #pragma unroll
        for (int t = 0; t < TT; ++t) {
            Wh[((size_t)((b*HH + h)*TT + t)*NN + n)*FF + f] =
                __float2bfloat16(acc[q][t]);
        }
    }

    int t2 = lane & 15;
    if (t2 < TT) {
        int h2 = lane >> 4;
        float s1 = 0.f, s2 = 0.f;
        for (int c = 0; c < CC; ++c) {
            float v = hLw[c*TT + t2];
            s1 += v * p1[h2*CC + c];
            s2 += v * p2[h2*CC + c];
        }
        int idx = ((b*HH + h2)*TT + t2)*NN + n;
        e1[idx] = s1;
        e2[idx] = s2;
    }
}

// ---------------------------------------------------------------------------
// K2T: Wh[bht][n<500][64] -> WhT[bht][f=64][m=512] bf16, m>=500 zeroed.
// ---------------------------------------------------------------------------
__global__ __launch_bounds__(256) void k2t(const ushort_t* __restrict__ Wh,
                                           ushort_t* __restrict__ WhT) {
    __shared__ ushort_t tile[64*512];     // 64 KB
    int wid  = threadIdx.x >> 6;
    int lane = threadIdx.x & 63;
    int bht  = blockIdx.x;
    const ushort_t* src = Wh + (size_t)bht * NN * FF;

    for (int task = wid; task < 64; task += 4) {
        int i  = task >> 3;               // m-block of 64
        int fo = task & 7;                // f-octet
        int m  = i*64 + lane;
        short8 v = {0,0,0,0,0,0,0,0};
        if (m < NN) v = *(const short8*)(src + m*FF + fo*8);
        #pragma unroll
        for (int j = 0; j < 8; ++j)
            tile[(fo*8 + j)*512 + m] = (ushort_t)v[j];
    }
    __syncthreads();

    ushort_t* dst = WhT + (size_t)bht * 64 * 512;
    for (int f = wid; f < 64; f += 4) {
        short8 v = *(const short8*)&tile[f*512 + lane*8];
        *(short8*)(dst + f*512 + lane*8) = v;
    }
}

// ---------------------------------------------------------------------------
// K3: attention PV via MFMA, K-chunked densification.
// Block = (bht, rb = quarter of rows).  Grid 384*4 = 1536 blocks.
// Per wave: 2 tiles of 16 rows.  Per tile: 4 m-chunks of 128:
//   zero 16x136-ushort A-chunk (4.25 KB) -> scatter exp(scores) (cols sorted,
//   per-row chunk slice from cstart4) -> 4 MFMA K-iters (A from LDS,
//   B 16B-contig from WhT global/L2).  Row-sum via all-ones B frag,
//   accumulated across chunks.  LDS 17.4 KB/block.
// ---------------------------------------------------------------------------
__global__ __launch_bounds__(256) void k3_attn(const ushort_t* __restrict__ WhT,
                                               const float* __restrict__ e1,
                                               const float* __restrict__ e2,
                                               const int* __restrict__ deg,
                                               const int* __restrict__ cols,
                                               const int4* __restrict__ cstart,
                                               ushort_t* __restrict__ hprB) {
    __shared__ ushort_t A[4][16*AST];     // 4 x 4352 B = 17408 B
    int wid  = threadIdx.x >> 6;
    int lane = threadIdx.x & 63;
    int bidx = blockIdx.x;
    int bht  = bidx >> 2;
    int rb   = bidx & 3;
    int b    = bht / NBT;
    int ht   = bht % NBT;

    const float* e1p = e1 + (size_t)bht * NN;
    const float* e2p = e2 + (size_t)bht * NN;
    const ushort_t* WT = WhT + (size_t)bht * 64 * 512;
    ushort_t* Aw = A[wid];

    int quad = lane >> 4;                 // 0..3
    int r    = lane & 15;                 // A-row / B-col / C-col
    int rr   = lane >> 2;                 // scatter row 0..15
    int j4   = lane & 3;                  // scatter sub-lane

    const short8 ONES = {0x3F80,0x3F80,0x3F80,0x3F80,
                         0x3F80,0x3F80,0x3F80,0x3F80}; // bf16 1.0 x8

    for (int u = 0; u < 2; ++u) {
        int n0 = rb*128 + (wid*2 + u)*16;
        int nrow = n0 + rr;

        int4 cs4 = make_int4(0,0,0,0);
        int dgv = 0;
        float e1v = 0.f;
        if (nrow < NN) {
            cs4 = cstart[nrow];
            dgv = deg[nrow];
            e1v = e1p[nrow];
        }

        floatx4 C[4];
        floatx4 Cs = {0.f,0.f,0.f,0.f};
        #pragma unroll
        for (int ft = 0; ft < 4; ++ft) C[ft] = (floatx4){0.f,0.f,0.f,0.f};

        for (int kc = 0; kc < 4; ++kc) {
            // zero A-chunk
            {
                short8 z = {0,0,0,0,0,0,0,0};
                short8* Az = (short8*)Aw;
                for (int i = lane; i < 16*AST/8; i += 64) Az[i] = z;
            }
            __builtin_amdgcn_s_waitcnt(0);

            // scatter this chunk's edges (sorted cols -> contiguous slice)
            int s0 = (kc==0) ? cs4.x : (kc==1) ? cs4.y : (kc==2) ? cs4.z : cs4.w;
            int s1 = (kc==0) ? cs4.y : (kc==1) ? cs4.z : (kc==2) ? cs4.w : dgv;
            if (nrow < NN) {
                const int* crow = cols + nrow*DSTRIDE;
                for (int s = s0 + j4; s < s1; s += 4) {
                    int m = crow[s];
                    float sc = e1v + e2p[m];
                    sc = sc > 0.f ? sc : 0.2f*sc;
                    Aw[rr*AST + (m - kc*128)] = f2bf(__expf(sc));
                }
            }
            // compiler inserts lgkm wait before dependent ds_read

            #pragma unroll
            for (int ki = 0; ki < 4; ++ki) {
                short8 a = *(const short8*)&Aw[r*AST + ki*32 + quad*8];
                int kg = kc*128 + ki*32 + quad*8;
                #pragma unroll
                for (int ft = 0; ft < 4; ++ft) {
                    short8 bfr = *(const short8*)(WT + (size_t)(ft*16 + r)*512 + kg);
                    C[ft] = __builtin_amdgcn_mfma_f32_16x16x32_bf16(a, bfr, C[ft], 0, 0, 0);
                }
                Cs = __builtin_amdgcn_mfma_f32_16x16x32_bf16(a, ONES, Cs, 0, 0, 0);
            }
        }

        // epilogue: scale by 1/lsum, ELU, store bf16 node-major
        #pragma unroll
        for (int reg = 0; reg < 4; ++reg) {
            int row = quad*4 + reg;
            int n = n0 + row;
            if (n < NN) {
                float inv = 1.0f / Cs[reg];
                size_t base = ((size_t)(b*NN + n)*NBT + ht)*FF;
                #pragma unroll
                for (int ft = 0; ft < 4; ++ft) {
                    float v = C[ft][reg] * inv;
                    v = v > 0.f ? v : __expf(v) - 1.f;
                    hprB[base + ft*16 + r] = f2bf(v);
                }
            }
        }
    }
}

// ---------------------------------------------------------------------------
// K4: head-mix 1x1 conv + residual via MFMA (unchanged from R5).
// ---------------------------------------------------------------------------
__global__ __launch_bounds__(256) void k4_mfma(const ushort_t* __restrict__ hprB,
                                               const ushort_t* __restrict__ WgB,
                                               const float* __restrict__ bg,
                                               const float* __restrict__ xT,
                                               float* __restrict__ hnext) {
    int wid  = threadIdx.x >> 6;
    int lane = threadIdx.x & 63;
    int quad = lane >> 4;
    int r    = lane & 15;

    short8 Afr[4][8];
    #pragma unroll
    for (int ot = 0; ot < 4; ++ot)
        #pragma unroll
        for (int kc = 0; kc < 8; ++kc)
            Afr[ot][kc] = *(const short8*)(WgB + (size_t)(ot*16 + r)*HF + kc*32 + quad*8);

    float4 bgv[4];
    #pragma unroll
    for (int ot = 0; ot < 4; ++ot)
        bgv[ot] = *(const float4*)(bg + ot*16 + quad*4);

    int tcl = r < TT ? r : TT-1;

    for (int u = 0; u < 4; ++u) {
        int node = blockIdx.x*16 + wid*4 + u;
        const ushort_t* P = hprB + (size_t)node * (NBT*FF);

        floatx4 C[4];
        #pragma unroll
        for (int ot = 0; ot < 4; ++ot) C[ot] = (floatx4){0.f,0.f,0.f,0.f};

        #pragma unroll
        for (int kc = 0; kc < 8; ++kc) {
            int k = kc*32 + quad*8;
            int h = k >> 6, f0 = k & 63;
            short8 bfr = *(const short8*)(P + (h*TT + tcl)*FF + f0);
            #pragma unroll
            for (int ot = 0; ot < 4; ++ot)
                C[ot] = __builtin_amdgcn_mfma_f32_16x16x32_bf16(Afr[ot][kc], bfr, C[ot], 0, 0, 0);
        }

        if (r < TT) {
            float* hout = hnext + (size_t)node * CT;
            const float* xp = xT + (size_t)node * CT;
            #pragma unroll
            for (int ot = 0; ot < 4; ++ot) {
                #pragma unroll
                for (int reg = 0; reg < 4; ++reg) {
                    int o = ot*16 + quad*4 + reg;
                    float v = C[ot][reg] + bgv[ot][reg];
                    hout[o*TT + r] = 0.05f*xp[o*TT + r] + 0.95f*v;
                }
            }
        }
    }
}

// ---------------------------------------------------------------------------
// K5: final mix (unchanged). out = bm + Wm @ [xT|h1|h2] per node.
// ---------------------------------------------------------------------------
__global__ __launch_bounds__(256) void k5_final(const float* __restrict__ xT,
                                                const float* __restrict__ h1,
                                                const float* __restrict__ h2,
                                                const float* __restrict__ WmT,
                                                const float* __restrict__ bm,
                                                float* __restrict__ out) {
    __shared__ float sL[4][3][CT];
    int wid  = threadIdx.x >> 6;
    int lane = threadIdx.x & 63;
    int gidx = blockIdx.x * 4 + wid;
    int b = gidx / NN, n = gidx % NN;

    {
        const float4* s0 = (const float4*)(xT + (size_t)gidx*CT);
        const float4* s1 = (const float4*)(h1 + (size_t)gidx*CT);
        const float4* s2 = (const float4*)(h2 + (size_t)gidx*CT);
        float4* d0 = (float4*)sL[wid][0];
        float4* d1 = (float4*)sL[wid][1];
        float4* d2 = (float4*)sL[wid][2];
        for (int i = lane; i < CT/4; i += 64) {
            d0[i] = s0[i]; d1[i] = s1[i]; d2[i] = s2[i];
        }
    }
    __syncthreads();

    float (*S)[CT] = sL[wid];
    int ob = lane & 15;
    int tq = lane >> 4;

    float acc[4][3];
    #pragma unroll
    for (int oi = 0; oi < 4; ++oi) {
        float bv = bm[ob + 16*oi];
        #pragma unroll
        for (int ti = 0; ti < 3; ++ti) acc[oi][ti] = bv;
    }

    for (int c = 0; c < CC; ++c) {
        float v0[3], v1[3], v2[3];
        #pragma unroll
        for (int ti = 0; ti < 3; ++ti) {
            int t = tq + 4*ti;
            v0[ti] = S[0][c*TT + t];
            v1[ti] = S[1][c*TT + t];
            v2[ti] = S[2][c*TT + t];
        }
        #pragma unroll
        for (int oi = 0; oi < 4; ++oi) {
            int o = ob + 16*oi;
            float w0 = WmT[(c       )*64 + o];
            float w1 = WmT[(CC  + c )*64 + o];
            float w2 = WmT[(2*CC + c)*64 + o];
            #pragma unroll
            for (int ti = 0; ti < 3; ++ti) {
                acc[oi][ti] += v0[ti]*w0 + v1[ti]*w1 + v2[ti]*w2;
            }
        }
    }

    #pragma unroll
    for (int oi = 0; oi < 4; ++oi) {
        int o = ob + 16*oi;
        #pragma unroll
        for (int ti = 0; ti < 3; ++ti) {
            int t = tq + 4*ti;
            out[((b*CC + o)*NN + n)*TT + t] = acc[oi][ti];
        }
    }
}

// ---------------------------------------------------------------------------
extern "C" void kernel_launch(void* const* d_in, const int* in_sizes, int n_in,
                              void* d_out, int out_size, void* d_ws, size_t ws_size,
                              hipStream_t stream) {
    const float* x   = (const float*)d_in[0];
    const float* adj = (const float*)d_in[1];
    const float* W   = (const float*)d_in[2];
    const float* a1  = (const float*)d_in[3];
    const float* a2  = (const float*)d_in[4];
    const float* Wg  = (const float*)d_in[5];
    const float* bg  = (const float*)d_in[6];
    const float* Wm  = (const float*)d_in[7];
    const float* bm  = (const float*)d_in[8];
    float* out = (float*)d_out;

    char* ws = (char*)d_ws;
    size_t off = 0;
    auto alloc = [&](size_t bytes) -> void* {
        void* p = ws + off;
        off += (bytes + 255) & ~(size_t)255;
        return p;
    };

    int*   deg  = (int*)  alloc(NN * sizeof(int));
    int*   cols = (int*)  alloc((size_t)NN * DSTRIDE * sizeof(int));
    int4*  cstart = (int4*)alloc(NN * sizeof(int4));
    float* p1   = (float*)alloc(HH*CC * sizeof(float));
    float* p2   = (float*)alloc(HH*CC * sizeof(float));
    float* WmT  = (float*)alloc(3*CC*CC * sizeof(float));
    ushort_t* WgB = (ushort_t*)alloc((size_t)FF*HF * 2);
    float* xT   = (float*)alloc((size_t)NNODE * CT * sizeof(float));        // 12.3 MB
    ushort_t* Wh   = (ushort_t*)alloc((size_t)NROWS * FF * 2);              // 24.6 MB
    ushort_t* WhT  = (ushort_t*)alloc((size_t)NBHT * 64 * 512 * 2);         // 25.2 MB
    ushort_t* hprB = (ushort_t*)alloc((size_t)NNODE * NBT * FF * 2);        // 24.6 MB
    float* e1   = (float*)alloc((size_t)NROWS * sizeof(float));
    float* e2   = (float*)alloc((size_t)NROWS * sizeof(float));
    float* h1   = (float*)alloc((size_t)NNODE * CT * sizeof(float));        // 12.3 MB
    float* h2   = (float*)alloc((size_t)NNODE * CT * sizeof(float));        // 12.3 MB
    (void)ws_size;

    k0_build<<<125, 256, 0, stream>>>(adj, deg, cols, cstart);
    k6_xt   <<<256, 256, 0, stream>>>(x, xT);
    k1_prep <<<114, 256, 0, stream>>>(W, a1, a2, Wm, Wg, p1, p2, WmT, WgB);

    // layer 1
    k2_wh_e <<<NNODE/4, 256, 0, stream>>>(xT, W, p1, p2, (__hip_bfloat16*)Wh, e1, e2);
    k2t     <<<NBHT,    256, 0, stream>>>(Wh, WhT);
    k3_attn <<<NBHT*4,  256, 0, stream>>>(WhT, e1, e2, deg, cols, cstart, hprB);
    k4_mfma <<<NNODE/16,256, 0, stream>>>(hprB, WgB, bg, xT, h1);

    // layer 2
    k2_wh_e <<<NNODE/4, 256, 0, stream>>>(h1, W, p1, p2, (__hip_bfloat16*)Wh, e1, e2);
    k2t     <<<NBHT,    256, 0, stream>>>(Wh, WhT);
    k3_attn <<<NBHT*4,  256, 0, stream>>>(WhT, e1, e2, deg, cols, cstart, hprB);
    k4_mfma <<<NNODE/16,256, 0, stream>>>(hprB, WgB, bg, xT, h2);

    // final
    k5_final<<<NNODE/4, 256, 0, stream>>>(xT, h1, h2, WmT, bm, out);
}

// Round 7
// 410.292 us; speedup vs baseline: 1.3457x; 1.1089x over previous
//
#include <hip/hip_runtime.h>
#include <hip/hip_bf16.h>
#include <math.h>

#define BB 8
#define CC 64
#define NN 500
#define TT 12
#define HH 4
#define FF 64
#define CT (CC*TT)      // 768
#define HF (HH*FF)      // 256
#define NBT (HH*TT)     // 48
#define NBHT (BB*NBT)   // 384
#define NROWS (BB*HH*TT*NN)  // 192000
#define NNODE (BB*NN)   // 4000

typedef unsigned short ushort_t;
typedef unsigned int uint_t;
typedef __attribute__((ext_vector_type(8))) short short8;
typedef __attribute__((ext_vector_type(4))) float floatx4;

static __device__ __forceinline__ ushort_t f2bf(float v) {
    __hip_bfloat16 h = __float2bfloat16(v);
    ushort_t u;
    __builtin_memcpy(&u, &h, 2);
    return u;
}

// RNE f32->bf16 bits (matches __float2bfloat16 for finite values)
static __device__ __forceinline__ uint_t rnebf(float x) {
    uint_t u = __float_as_uint(x);
    return (u + 0x7FFFu + ((u >> 16) & 1u)) >> 16;
}

// ---------------------------------------------------------------------------
// K0: dense mask[512][512] (ushort 1/0): mask = (adj + I) > 0, zero-padded.
// ---------------------------------------------------------------------------
__global__ __launch_bounds__(256) void k0_mask(const float* __restrict__ adj,
                                               ushort_t* __restrict__ maskB) {
    int idx = blockIdx.x * 256 + threadIdx.x;   // < 512*512
    int n = idx >> 9, m = idx & 511;
    ushort_t v = 0;
    if (n < NN && m < NN)
        v = (adj[n*NN + m] > 0.f || m == n) ? 1 : 0;
    maskB[idx] = v;
}

// ---------------------------------------------------------------------------
// K6: transpose x [B,C,N,T] -> xT [(b*N+n)*768 + c*12 + t] (node-major).
// ---------------------------------------------------------------------------
__global__ __launch_bounds__(256) void k6_xt(const float* __restrict__ x,
                                             float* __restrict__ xT) {
    __shared__ float tile[16*776];   // 49664 B
    int b  = blockIdx.x >> 5;
    int n0 = (blockIdx.x & 31) * 16;
    for (int idx = threadIdx.x; idx < CC*16*TT; idx += 256) {
        int c   = idx / (16*TT);
        int rem = idx % (16*TT);
        int nl  = rem / TT;
        int t   = rem % TT;
        int n   = n0 + nl;
        if (n < NN)
            tile[nl*776 + c*TT + t] = x[((b*CC + c)*NN + n)*TT + t];
    }
    __syncthreads();
    for (int idx = threadIdx.x; idx < 16*CT; idx += 256) {
        int nl = idx / CT;
        int j  = idx % CT;
        int n  = n0 + nl;
        if (n < NN)
            xT[(size_t)(b*NN + n)*CT + j] = tile[nl*776 + j];
    }
}

// ---------------------------------------------------------------------------
// K1: prep. p1/p2 folded attention vectors; WmT transpose; WgB = bf16(Wg).
// ---------------------------------------------------------------------------
__global__ __launch_bounds__(256) void k1_prep(const float* __restrict__ W,
                                               const float* __restrict__ a1,
                                               const float* __restrict__ a2,
                                               const float* __restrict__ Wm,
                                               const float* __restrict__ Wg,
                                               float* __restrict__ p1,
                                               float* __restrict__ p2,
                                               float* __restrict__ WmT,
                                               ushort_t* __restrict__ WgB) {
    int idx = blockIdx.x * 256 + threadIdx.x;
    if (idx < HH*CC) {
        int h = idx / CC, c = idx % CC;
        float s1 = 0.f, s2 = 0.f;
        for (int f = 0; f < FF; ++f) {
            float w = W[(h*CC + c)*FF + f];
            s1 += w * a1[h*FF + f];
            s2 += w * a2[h*FF + f];
        }
        p1[idx] = s1; p2[idx] = s2;
    }
    int j = idx - HH*CC;
    if (j >= 0 && j < 3*CC*CC) {
        int c = j >> 6, o = j & 63;
        WmT[j] = Wm[o*(3*CC) + c];
    }
    int j2 = idx - (HH*CC + 3*CC*CC);
    if (j2 >= 0 && j2 < FF*HF) {
        WgB[j2] = f2bf(Wg[j2]);
    }
}

// ---------------------------------------------------------------------------
// K2: Wh[bht][n][f] (bf16) = sum_c h[node][c,t] * W[h,c,f]; e1/e2 via p1/p2.
// ---------------------------------------------------------------------------
__global__ __launch_bounds__(256) void k2_wh_e(const float* __restrict__ hin,
                                               const float* __restrict__ W,
                                               const float* __restrict__ p1,
                                               const float* __restrict__ p2,
                                               __hip_bfloat16* __restrict__ Wh,
                                               float* __restrict__ e1,
                                               float* __restrict__ e2) {
    __shared__ float hL[4][CT];
    int wid  = threadIdx.x >> 6;
    int lane = threadIdx.x & 63;
    int gidx = blockIdx.x * 4 + wid;
    int b = gidx / NN, n = gidx % NN;

    {
        const float4* src = (const float4*)(hin + (size_t)gidx * CT);
        float4* dst = (float4*)hL[wid];
        for (int i = lane; i < CT/4; i += 64) dst[i] = src[i];
    }
    __syncthreads();

    const float*  hLw = hL[wid];
    const float4* h4  = (const float4*)hLw;
    int h  = lane >> 4;
    int fb = lane & 15;

    float acc[4][TT];
    #pragma unroll
    for (int q = 0; q < 4; ++q)
        #pragma unroll
        for (int t = 0; t < TT; ++t) acc[q][t] = 0.f;

    for (int c = 0; c < CC; ++c) {
        float4 v0 = h4[c*3+0], v1 = h4[c*3+1], v2 = h4[c*3+2];
        float hv[12] = {v0.x,v0.y,v0.z,v0.w, v1.x,v1.y,v1.z,v1.w,
                        v2.x,v2.y,v2.z,v2.w};
        const float* Wc = W + (h*CC + c)*FF + fb;
        float w0 = Wc[0], w1 = Wc[16], w2 = Wc[32], w3 = Wc[48];
        #pragma unroll
        for (int t = 0; t < TT; ++t) {
            acc[0][t] += hv[t]*w0;
            acc[1][t] += hv[t]*w1;
            acc[2][t] += hv[t]*w2;
            acc[3][t] += hv[t]*w3;
        }
    }
    #pragma unroll
    for (int q = 0; q < 4; ++q) {
        int f = fb + 16*q;
        #pragma unroll
        for (int t = 0; t < TT; ++t) {
            Wh[((size_t)((b*HH + h)*TT + t)*NN + n)*FF + f] =
                __float2bfloat16(acc[q][t]);
        }
    }

    int t2 = lane & 15;
    if (t2 < TT) {
        int h2 = lane >> 4;
        float s1 = 0.f, s2 = 0.f;
        for (int c = 0; c < CC; ++c) {
            float v = hLw[c*TT + t2];
            s1 += v * p1[h2*CC + c];
            s2 += v * p2[h2*CC + c];
        }
        int idx = ((b*HH + h2)*TT + t2)*NN + n;
        e1[idx] = s1;
        e2[idx] = s2;
    }
}

// ---------------------------------------------------------------------------
// K2T: Wh[bht][n<500][64] -> WhT[bht][f=64][m=512] bf16, m>=500 zeroed.
// ---------------------------------------------------------------------------
__global__ __launch_bounds__(256) void k2t(const ushort_t* __restrict__ Wh,
                                           ushort_t* __restrict__ WhT) {
    __shared__ ushort_t tile[64*512];     // 64 KB
    int wid  = threadIdx.x >> 6;
    int lane = threadIdx.x & 63;
    int bht  = blockIdx.x;
    const ushort_t* src = Wh + (size_t)bht * NN * FF;

    for (int task = wid; task < 64; task += 4) {
        int i  = task >> 3;               // m-block of 64
        int fo = task & 7;                // f-octet
        int m  = i*64 + lane;
        short8 v = {0,0,0,0,0,0,0,0};
        if (m < NN) v = *(const short8*)(src + m*FF + fo*8);
        #pragma unroll
        for (int j = 0; j < 8; ++j)
            tile[(fo*8 + j)*512 + m] = (ushort_t)v[j];
    }
    __syncthreads();

    ushort_t* dst = WhT + (size_t)bht * 64 * 512;
    for (int f = wid; f < 64; f += 4) {
        short8 v = *(const short8*)&tile[f*512 + lane*8];
        *(short8*)(dst + f*512 + lane*8) = v;
    }
}

// ---------------------------------------------------------------------------
// K3: attention PV via MFMA, register-built dense A (no LDS A-tile, no
// scatter, no waits).  Block = (bht, rb quarter).  4 waves x 2 row-tiles.
// Per ki (K=32 chunk): load 4 B-frags from WhT (shared by both tiles);
// per tile, each lane computes its 8 A-slots directly:
//   A[n0+r][kb+j] = mask[n][kb+j] ? exp2(max(s,0.2s)) : 0,
//   s = (e1[n]+e2[kb+j])*log2e  (e1/e2 pre-scaled, staged in LDS).
// Row-sum via all-ones B frag.  Shift-free softmax as before (bit-identical
// numerics to R6: same RNE bf16, same exp basis).
// ---------------------------------------------------------------------------
__global__ __launch_bounds__(256, 4) void k3_attn(const ushort_t* __restrict__ WhT,
                                                  const float* __restrict__ e1,
                                                  const float* __restrict__ e2,
                                                  const ushort_t* __restrict__ maskB,
                                                  ushort_t* __restrict__ hprB) {
    __shared__ float e2s[512];
    __shared__ float e1s[128];
    int tid  = threadIdx.x;
    int wid  = tid >> 6;
    int lane = tid & 63;
    int bht  = blockIdx.x >> 2;
    int rb   = blockIdx.x & 3;
    int b    = bht / NBT;
    int ht   = bht % NBT;

    const float* e1p = e1 + (size_t)bht * NN;
    const float* e2p = e2 + (size_t)bht * NN;
    const ushort_t* WT = WhT + (size_t)bht * 64 * 512;
    const float L2E = 1.4426950408889634f;

    {
        int i = tid;
        e2s[i] = (i < NN) ? e2p[i] * L2E : 0.f;
        i = tid + 256;
        e2s[i] = (i < NN) ? e2p[i] * L2E : 0.f;
        if (tid < 128) {
            int rg = rb*128 + tid;
            e1s[tid] = (rg < NN) ? e1p[rg] * L2E : 0.f;
        }
    }
    __syncthreads();

    int quad = lane >> 4;                 // 0..3
    int r    = lane & 15;                 // A-row / B-col / C-col

    const short8 ONES = {0x3F80,0x3F80,0x3F80,0x3F80,
                         0x3F80,0x3F80,0x3F80,0x3F80}; // bf16 1.0 x8

    int t0 = wid*32;                      // tile a local row base
    int t1 = wid*32 + 16;                 // tile b
    int n0a = rb*128 + t0;
    int n0b = rb*128 + t1;
    float e1a = e1s[t0 + r];
    float e1b = e1s[t1 + r];
    const ushort_t* mra = maskB + (size_t)(n0a + r) * 512;
    const ushort_t* mrb = maskB + (size_t)(n0b + r) * 512;

    floatx4 Ca[4], Cb[4];
    floatx4 Csa = {0.f,0.f,0.f,0.f}, Csb = {0.f,0.f,0.f,0.f};
    #pragma unroll
    for (int ft = 0; ft < 4; ++ft) {
        Ca[ft] = (floatx4){0.f,0.f,0.f,0.f};
        Cb[ft] = (floatx4){0.f,0.f,0.f,0.f};
    }

    for (int ki = 0; ki < 16; ++ki) {
        int kb = ki*32 + quad*8;

        short8 bfr[4];
        #pragma unroll
        for (int ft = 0; ft < 4; ++ft)
            bfr[ft] = *(const short8*)(WT + (size_t)(ft*16 + r)*512 + kb);

        float4 ea = *(const float4*)&e2s[kb];
        float4 eb = *(const float4*)&e2s[kb + 4];
        float ev[8] = {ea.x, ea.y, ea.z, ea.w, eb.x, eb.y, eb.z, eb.w};

        // ---- tile a ----
        {
            short8 mk = *(const short8*)&mra[kb];
            union { uint_t u[4]; short8 s; } av;
            #pragma unroll
            for (int p = 0; p < 4; ++p) {
                float s0 = e1a + ev[2*p];
                float s1 = e1a + ev[2*p+1];
                float g0 = fmaxf(s0, 0.2f*s0);
                float g1 = fmaxf(s1, 0.2f*s1);
                float x0 = __builtin_amdgcn_exp2f(g0);
                float x1 = __builtin_amdgcn_exp2f(g1);
                x0 = mk[2*p]   ? x0 : 0.f;
                x1 = mk[2*p+1] ? x1 : 0.f;
                av.u[p] = (rnebf(x1) << 16) | rnebf(x0);
            }
            #pragma unroll
            for (int ft = 0; ft < 4; ++ft)
                Ca[ft] = __builtin_amdgcn_mfma_f32_16x16x32_bf16(av.s, bfr[ft], Ca[ft], 0, 0, 0);
            Csa = __builtin_amdgcn_mfma_f32_16x16x32_bf16(av.s, ONES, Csa, 0, 0, 0);
        }
        // ---- tile b ----
        {
            short8 mk = *(const short8*)&mrb[kb];
            union { uint_t u[4]; short8 s; } av;
            #pragma unroll
            for (int p = 0; p < 4; ++p) {
                float s0 = e1b + ev[2*p];
                float s1 = e1b + ev[2*p+1];
                float g0 = fmaxf(s0, 0.2f*s0);
                float g1 = fmaxf(s1, 0.2f*s1);
                float x0 = __builtin_amdgcn_exp2f(g0);
                float x1 = __builtin_amdgcn_exp2f(g1);
                x0 = mk[2*p]   ? x0 : 0.f;
                x1 = mk[2*p+1] ? x1 : 0.f;
                av.u[p] = (rnebf(x1) << 16) | rnebf(x0);
            }
            #pragma unroll
            for (int ft = 0; ft < 4; ++ft)
                Cb[ft] = __builtin_amdgcn_mfma_f32_16x16x32_bf16(av.s, bfr[ft], Cb[ft], 0, 0, 0);
            Csb = __builtin_amdgcn_mfma_f32_16x16x32_bf16(av.s, ONES, Csb, 0, 0, 0);
        }
    }

    // epilogue: scale by 1/lsum, ELU, store bf16 node-major
    #pragma unroll
    for (int reg = 0; reg < 4; ++reg) {
        int row = quad*4 + reg;
        int n = n0a + row;
        if (n < NN) {
            float inv = 1.0f / Csa[reg];
            size_t base = ((size_t)(b*NN + n)*NBT + ht)*FF;
            #pragma unroll
            for (int ft = 0; ft < 4; ++ft) {
                float v = Ca[ft][reg] * inv;
                v = v > 0.f ? v : __expf(v) - 1.f;
                hprB[base + ft*16 + r] = f2bf(v);
            }
        }
        n = n0b + row;
        if (n < NN) {
            float inv = 1.0f / Csb[reg];
            size_t base = ((size_t)(b*NN + n)*NBT + ht)*FF;
            #pragma unroll
            for (int ft = 0; ft < 4; ++ft) {
                float v = Cb[ft][reg] * inv;
                v = v > 0.f ? v : __expf(v) - 1.f;
                hprB[base + ft*16 + r] = f2bf(v);
            }
        }
    }
}

// ---------------------------------------------------------------------------
// K4: head-mix 1x1 conv + residual via MFMA (unchanged from R5/R6).
// ---------------------------------------------------------------------------
__global__ __launch_bounds__(256) void k4_mfma(const ushort_t* __restrict__ hprB,
                                               const ushort_t* __restrict__ WgB,
                                               const float* __restrict__ bg,
                                               const float* __restrict__ xT,
                                               float* __restrict__ hnext) {
    int wid  = threadIdx.x >> 6;
    int lane = threadIdx.x & 63;
    int quad = lane >> 4;
    int r    = lane & 15;

    short8 Afr[4][8];
    #pragma unroll
    for (int ot = 0; ot < 4; ++ot)
        #pragma unroll
        for (int kc = 0; kc < 8; ++kc)
            Afr[ot][kc] = *(const short8*)(WgB + (size_t)(ot*16 + r)*HF + kc*32 + quad*8);

    float4 bgv[4];
    #pragma unroll
    for (int ot = 0; ot < 4; ++ot)
        bgv[ot] = *(const float4*)(bg + ot*16 + quad*4);

    int tcl = r < TT ? r : TT-1;

    for (int u = 0; u < 4; ++u) {
        int node = blockIdx.x*16 + wid*4 + u;
        const ushort_t* P = hprB + (size_t)node * (NBT*FF);

        floatx4 C[4];
        #pragma unroll
        for (int ot = 0; ot < 4; ++ot) C[ot] = (floatx4){0.f,0.f,0.f,0.f};

        #pragma unroll
        for (int kc = 0; kc < 8; ++kc) {
            int k = kc*32 + quad*8;
            int h = k >> 6, f0 = k & 63;
            short8 bfr = *(const short8*)(P + (h*TT + tcl)*FF + f0);
            #pragma unroll
            for (int ot = 0; ot < 4; ++ot)
                C[ot] = __builtin_amdgcn_mfma_f32_16x16x32_bf16(Afr[ot][kc], bfr, C[ot], 0, 0, 0);
        }

        if (r < TT) {
            float* hout = hnext + (size_t)node * CT;
            const float* xp = xT + (size_t)node * CT;
            #pragma unroll
            for (int ot = 0; ot < 4; ++ot) {
                #pragma unroll
                for (int reg = 0; reg < 4; ++reg) {
                    int o = ot*16 + quad*4 + reg;
                    float v = C[ot][reg] + bgv[ot][reg];
                    hout[o*TT + r] = 0.05f*xp[o*TT + r] + 0.95f*v;
                }
            }
        }
    }
}

// ---------------------------------------------------------------------------
// K5: final mix (unchanged). out = bm + Wm @ [xT|h1|h2] per node.
// ---------------------------------------------------------------------------
__global__ __launch_bounds__(256) void k5_final(const float* __restrict__ xT,
                                                const float* __restrict__ h1,
                                                const float* __restrict__ h2,
                                                const float* __restrict__ WmT,
                                                const float* __restrict__ bm,
                                                float* __restrict__ out) {
    __shared__ float sL[4][3][CT];
    int wid  = threadIdx.x >> 6;
    int lane = threadIdx.x & 63;
    int gidx = blockIdx.x * 4 + wid;
    int b = gidx / NN, n = gidx % NN;

    {
        const float4* s0 = (const float4*)(xT + (size_t)gidx*CT);
        const float4* s1 = (const float4*)(h1 + (size_t)gidx*CT);
        const float4* s2 = (const float4*)(h2 + (size_t)gidx*CT);
        float4* d0 = (float4*)sL[wid][0];
        float4* d1 = (float4*)sL[wid][1];
        float4* d2 = (float4*)sL[wid][2];
        for (int i = lane; i < CT/4; i += 64) {
            d0[i] = s0[i]; d1[i] = s1[i]; d2[i] = s2[i];
        }
    }
    __syncthreads();

    float (*S)[CT] = sL[wid];
    int ob = lane & 15;
    int tq = lane >> 4;

    float acc[4][3];
    #pragma unroll
    for (int oi = 0; oi < 4; ++oi) {
        float bv = bm[ob + 16*oi];
        #pragma unroll
        for (int ti = 0; ti < 3; ++ti) acc[oi][ti] = bv;
    }

    for (int c = 0; c < CC; ++c) {
        float v0[3], v1[3], v2[3];
        #pragma unroll
        for (int ti = 0; ti < 3; ++ti) {
            int t = tq + 4*ti;
            v0[ti] = S[0][c*TT + t];
            v1[ti] = S[1][c*TT + t];
            v2[ti] = S[2][c*TT + t];
        }
        #pragma unroll
        for (int oi = 0; oi < 4; ++oi) {
            int o = ob + 16*oi;
            float w0 = WmT[(c       )*64 + o];
            float w1 = WmT[(CC  + c )*64 + o];
            float w2 = WmT[(2*CC + c)*64 + o];
            #pragma unroll
            for (int ti = 0; ti < 3; ++ti) {
                acc[oi][ti] += v0[ti]*w0 + v1[ti]*w1 + v2[ti]*w2;
            }
        }
    }

    #pragma unroll
    for (int oi = 0; oi < 4; ++oi) {
        int o = ob + 16*oi;
        #pragma unroll
        for (int ti = 0; ti < 3; ++ti) {
            int t = tq + 4*ti;
            out[((b*CC + o)*NN + n)*TT + t] = acc[oi][ti];
        }
    }
}

// ---------------------------------------------------------------------------
extern "C" void kernel_launch(void* const* d_in, const int* in_sizes, int n_in,
                              void* d_out, int out_size, void* d_ws, size_t ws_size,
                              hipStream_t stream) {
    const float* x   = (const float*)d_in[0];
    const float* adj = (const float*)d_in[1];
    const float* W   = (const float*)d_in[2];
    const float* a1  = (const float*)d_in[3];
    const float* a2  = (const float*)d_in[4];
    const float* Wg  = (const float*)d_in[5];
    const float* bg  = (const float*)d_in[6];
    const float* Wm  = (const float*)d_in[7];
    const float* bm  = (const float*)d_in[8];
    float* out = (float*)d_out;

    char* ws = (char*)d_ws;
    size_t off = 0;
    auto alloc = [&](size_t bytes) -> void* {
        void* p = ws + off;
        off += (bytes + 255) & ~(size_t)255;
        return p;
    };

    ushort_t* maskB = (ushort_t*)alloc((size_t)512 * 512 * 2);              // 512 KB
    float* p1   = (float*)alloc(HH*CC * sizeof(float));
    float* p2   = (float*)alloc(HH*CC * sizeof(float));
    float* WmT  = (float*)alloc(3*CC*CC * sizeof(float));
    ushort_t* WgB = (ushort_t*)alloc((size_t)FF*HF * 2);
    float* xT   = (float*)alloc((size_t)NNODE * CT * sizeof(float));        // 12.3 MB
    ushort_t* Wh   = (ushort_t*)alloc((size_t)NROWS * FF * 2);              // 24.6 MB
    ushort_t* WhT  = (ushort_t*)alloc((size_t)NBHT * 64 * 512 * 2);         // 25.2 MB
    ushort_t* hprB = (ushort_t*)alloc((size_t)NNODE * NBT * FF * 2);        // 24.6 MB
    float* e1   = (float*)alloc((size_t)NROWS * sizeof(float));
    float* e2   = (float*)alloc((size_t)NROWS * sizeof(float));
    float* h1   = (float*)alloc((size_t)NNODE * CT * sizeof(float));        // 12.3 MB
    float* h2   = (float*)alloc((size_t)NNODE * CT * sizeof(float));        // 12.3 MB
    (void)ws_size;

    k0_mask <<<1024, 256, 0, stream>>>(adj, maskB);
    k6_xt   <<<256,  256, 0, stream>>>(x, xT);
    k1_prep <<<114,  256, 0, stream>>>(W, a1, a2, Wm, Wg, p1, p2, WmT, WgB);

    // layer 1
    k2_wh_e <<<NNODE/4, 256, 0, stream>>>(xT, W, p1, p2, (__hip_bfloat16*)Wh, e1, e2);
    k2t     <<<NBHT,    256, 0, stream>>>(Wh, WhT);
    k3_attn <<<NBHT*4,  256, 0, stream>>>(WhT, e1, e2, maskB, hprB);
    k4_mfma <<<NNODE/16,256, 0, stream>>>(hprB, WgB, bg, xT, h1);

    // layer 2
    k2_wh_e <<<NNODE/4, 256, 0, stream>>>(h1, W, p1, p2, (__hip_bfloat16*)Wh, e1, e2);
    k2t     <<<NBHT,    256, 0, stream>>>(Wh, WhT);
    k3_attn <<<NBHT*4,  256, 0, stream>>>(WhT, e1, e2, maskB, hprB);
    k4_mfma <<<NNODE/16,256, 0, stream>>>(hprB, WgB, bg, xT, h2);

    // final
    k5_final<<<NNODE/4, 256, 0, stream>>>(xT, h1, h2, WmT, bm, out);
}